// Round 1
// baseline (1250.695 us; speedup 1.0000x reference)
//
#include <hip/hip_runtime.h>
#include <hip/hip_bf16.h>

typedef __bf16 bf16_t;
typedef __bf16 bf16x8 __attribute__((ext_vector_type(8)));
typedef float f32x4 __attribute__((ext_vector_type(4)));

constexpr int NODEMB = 128;
constexpr int HIDDEN = 128;
constexpr int EDGEMB = 128;
constexpr int NEDGES = 800000;

constexpr int W1S = 296;   // padded K stride (elements) for W1T: 288 used + 8 pad (bank spread)
constexpr int W2S = 136;   // padded K stride for W2T: 128 used + 8 pad
constexpr int HS  = 136;   // padded K stride for per-wave H buffer
constexpr int W1_ELEMS = HIDDEN * W1S;   // 37888
constexpr int W2_ELEMS = EDGEMB * W2S;   // 17408
constexpr int TILE_EDGES = 128;
constexpr int NTILES = NEDGES / TILE_EDGES;  // 6250 exactly

// ---------------------------------------------------------------------------
// Prep: build K-permuted, zero-padded, K-major bf16 weights in workspace.
// K-order: [0,128)=dst_hidden rows (orig 2..129), [128,256)=src_hidden rows
// (orig 132..259), 256=orig row 0, 257=row 1, 258=row 130, 259=row 131,
// 260=row 260 (distance), [261,296)=zero.
// ---------------------------------------------------------------------------
__global__ void prep_weights(const float* __restrict__ W1, const float* __restrict__ W2,
                             bf16_t* __restrict__ w1t, bf16_t* __restrict__ w2t) {
    int i = blockIdx.x * blockDim.x + threadIdx.x;
    if (i < W1_ELEMS) {
        int n = i / W1S, k = i - n * W1S;
        float v = 0.f;
        if (k < 128)       v = W1[(2 + k) * HIDDEN + n];
        else if (k < 256)  v = W1[(132 + (k - 128)) * HIDDEN + n];
        else if (k == 256) v = W1[0 * HIDDEN + n];
        else if (k == 257) v = W1[1 * HIDDEN + n];
        else if (k == 258) v = W1[130 * HIDDEN + n];
        else if (k == 259) v = W1[131 * HIDDEN + n];
        else if (k == 260) v = W1[260 * HIDDEN + n];
        w1t[n * W1S + k] = (bf16_t)v;
    } else if (i < W1_ELEMS + W2_ELEMS) {
        int j = i - W1_ELEMS;
        int n = j / W2S, k = j - n * W2S;
        float v = (k < 128) ? W2[k * EDGEMB + n] : 0.f;
        w2t[n * W2S + k] = (bf16_t)v;
    }
}

__device__ __forceinline__ bf16x8 cvt8(f32x4 lo, f32x4 hi) {
    bf16x8 t;
    t[0] = (bf16_t)lo[0]; t[1] = (bf16_t)lo[1]; t[2] = (bf16_t)lo[2]; t[3] = (bf16_t)lo[3];
    t[4] = (bf16_t)hi[0]; t[5] = (bf16_t)hi[1]; t[6] = (bf16_t)hi[2]; t[7] = (bf16_t)hi[3];
    return t;
}

// ---------------------------------------------------------------------------
// Main: 8 waves/block, each wave owns 16 edges/tile, all 128 output cols.
// A-fragments gathered straight from global (K-permuted layout -> contiguous
// float4 loads of node_hidden). Weights in LDS. h transposed via per-wave
// LDS buffer (no block barriers in the loop).
// ---------------------------------------------------------------------------
__global__ __launch_bounds__(512, 2) void edge_mlp(
    const float* __restrict__ node_features,
    const float* __restrict__ node_hidden,
    const float* __restrict__ distance,
    const int*   __restrict__ src_idx,
    const int*   __restrict__ dst_idx,
    const float* __restrict__ b1,
    const float* __restrict__ b2,
    const bf16_t* __restrict__ w1t,
    const bf16_t* __restrict__ w2t,
    float* __restrict__ out)
{
    __shared__ bf16_t sW[W1_ELEMS + W2_ELEMS];   // 110,592 B
    __shared__ bf16_t sH[8][16][HS];             //  34,816 B

    const int tid = threadIdx.x;

    // stage W1T+W2T (contiguous in ws) into LDS, 16B chunks
    {
        const uint4* gsrc = (const uint4*)w1t;
        uint4* ldst = (uint4*)sW;
        constexpr int CH = (W1_ELEMS + W2_ELEMS) / 8;  // 6912
        for (int i = tid; i < CH; i += 512) ldst[i] = gsrc[i];
    }
    __syncthreads();
    const bf16_t* sW1 = sW;
    const bf16_t* sW2 = sW + W1_ELEMS;

    const int wid  = tid >> 6;
    const int lane = tid & 63;
    const int r    = lane & 15;   // A row / B col within 16-tile
    const int g    = lane >> 4;   // k-subblock selector

    float b1v[8], b2v[8];
    #pragma unroll
    for (int nt = 0; nt < 8; ++nt) {
        b1v[nt] = b1[nt * 16 + r];
        b2v[nt] = b2[nt * 16 + r];
    }

    for (int tile = blockIdx.x; tile < NTILES; tile += gridDim.x) {
        const int ebase = tile * TILE_EDGES + wid * 16;
        const int e  = ebase + r;
        const int di = dst_idx[e];
        const int si = src_idx[e];
        const f32x4* dh = (const f32x4*)(node_hidden + (size_t)di * NODEMB);
        const f32x4* sh = (const f32x4*)(node_hidden + (size_t)si * NODEMB);

        // ---- gather A fragments (9 k-steps of 32) ----
        bf16x8 a[9];
        #pragma unroll
        for (int ks = 0; ks < 4; ++ks) {
            f32x4 lo = dh[ks * 8 + g * 2];
            f32x4 hi = dh[ks * 8 + g * 2 + 1];
            a[ks] = cvt8(lo, hi);
        }
        #pragma unroll
        for (int ks = 0; ks < 4; ++ks) {
            f32x4 lo = sh[ks * 8 + g * 2];
            f32x4 hi = sh[ks * 8 + g * 2 + 1];
            a[4 + ks] = cvt8(lo, hi);
        }
        {
            bf16x8 t;
            #pragma unroll
            for (int j = 0; j < 8; ++j) t[j] = (bf16_t)0.f;
            if (g == 0) {
                t[0] = (bf16_t)node_features[di * 2];
                t[1] = (bf16_t)node_features[di * 2 + 1];
                t[2] = (bf16_t)node_features[si * 2];
                t[3] = (bf16_t)node_features[si * 2 + 1];
                t[4] = (bf16_t)distance[e];
            }
            a[8] = t;
        }

        // ---- layer 1: [16 x 288] @ [288 x 128] ----
        f32x4 acc[8];
        #pragma unroll
        for (int nt = 0; nt < 8; ++nt) {
            float bv = b1v[nt];
            acc[nt][0] = bv; acc[nt][1] = bv; acc[nt][2] = bv; acc[nt][3] = bv;
        }
        #pragma unroll
        for (int ks = 0; ks < 9; ++ks) {
            #pragma unroll
            for (int nt = 0; nt < 8; ++nt) {
                bf16x8 b = *(const bf16x8*)&sW1[(nt * 16 + r) * W1S + ks * 32 + g * 8];
                acc[nt] = __builtin_amdgcn_mfma_f32_16x16x32_bf16(a[ks], b, acc[nt], 0, 0, 0);
            }
        }

        // ---- relu + transpose h through per-wave LDS ----
        // acc layout: col = lane&15, row = g*4+i  -> store as [row][k=col]
        #pragma unroll
        for (int nt = 0; nt < 8; ++nt) {
            #pragma unroll
            for (int i = 0; i < 4; ++i) {
                float h = acc[nt][i];
                h = h > 0.f ? h : 0.f;
                sH[wid][g * 4 + i][nt * 16 + r] = (bf16_t)h;
            }
        }
        // same-wave RAW on LDS: compiler inserts lgkmcnt wait
        bf16x8 ha[4];
        #pragma unroll
        for (int ks = 0; ks < 4; ++ks)
            ha[ks] = *(const bf16x8*)&sH[wid][r][ks * 32 + g * 8];

        // ---- layer 2: [16 x 128] @ [128 x 128] ----
        f32x4 acc2[8];
        #pragma unroll
        for (int nt = 0; nt < 8; ++nt) {
            float bv = b2v[nt];
            acc2[nt][0] = bv; acc2[nt][1] = bv; acc2[nt][2] = bv; acc2[nt][3] = bv;
        }
        #pragma unroll
        for (int ks = 0; ks < 4; ++ks) {
            #pragma unroll
            for (int nt = 0; nt < 8; ++nt) {
                bf16x8 b = *(const bf16x8*)&sW2[(nt * 16 + r) * W2S + ks * 32 + g * 8];
                acc2[nt] = __builtin_amdgcn_mfma_f32_16x16x32_bf16(ha[ks], b, acc2[nt], 0, 0, 0);
            }
        }

        // ---- relu + store out ----
        float* ob = out + (size_t)ebase * EDGEMB;
        #pragma unroll
        for (int nt = 0; nt < 8; ++nt) {
            #pragma unroll
            for (int i = 0; i < 4; ++i) {
                float v = acc2[nt][i];
                ob[(g * 4 + i) * EDGEMB + nt * 16 + r] = v > 0.f ? v : 0.f;
            }
        }
    }
}

extern "C" void kernel_launch(void* const* d_in, const int* in_sizes, int n_in,
                              void* d_out, int out_size, void* d_ws, size_t ws_size,
                              hipStream_t stream) {
    const float* node_features = (const float*)d_in[0];
    const float* node_hidden   = (const float*)d_in[1];
    const float* distance      = (const float*)d_in[2];
    const int*   src_idx       = (const int*)d_in[3];
    const int*   dst_idx       = (const int*)d_in[4];
    const float* W1 = (const float*)d_in[5];
    const float* b1 = (const float*)d_in[6];
    const float* W2 = (const float*)d_in[7];
    const float* b2 = (const float*)d_in[8];
    float* out = (float*)d_out;

    bf16_t* w1t = (bf16_t*)d_ws;
    bf16_t* w2t = w1t + W1_ELEMS;

    const int prepThreads = W1_ELEMS + W2_ELEMS;
    prep_weights<<<(prepThreads + 255) / 256, 256, 0, stream>>>(W1, W2, w1t, w2t);

    edge_mlp<<<256, 512, 0, stream>>>(node_features, node_hidden, distance,
                                      src_idx, dst_idx, b1, b2, w1t, w2t, out);
}